// Round 6
// baseline (111.737 us; speedup 1.0000x reference)
//
#include <hip/hip_runtime.h>

#define TPB 256

// r21: instruction-count round. r18 win = count cut; r20 depth cuts neutral
// => kernel is issue-limited, not chain-limited. Clip refactored onto the
// shared cross-matrix M[i][j]=cross(A_i,B_j):
//   aa(edge i, hp j) = M[i][j]-M[i][j+1]+cb_j   (rolling M, 2 ops)
//   bb               = s[i+1]-s[i]              (1 op, shared)
//   cpd (Green term)  = ca_i / cb_j             (free: shoelace terms)
// ~-400 VALU ops. NOT bit-exact vs r20 (reassociation); output is a single
// averaged scalar -> expected absmax ~1e-7. This round probes tolerance.
// __launch_bounds__(256,4) pins VGPR<=128 (4 waves/SIMD, grid-capped).
// Hull start tree, 8-chain Jarvis, epilogue, finalize: unchanged from r20.
__global__ __launch_bounds__(TPB, 4) void ciou_main(
    const float* __restrict__ A,
    const float* __restrict__ Bq,
    double* __restrict__ partial,
    int nbatch, int tail)
{
    const int t = threadIdx.x;
    const int i0 = blockIdx.x * TPB + t;
    const bool live = !tail || (i0 < nbatch);
    const int i = live ? i0 : (nbatch - 1);

    float ax0,ax1,ax2,ax3,ax4,ax5,ax6,ax7;
    float ay0,ay1,ay2,ay3,ay4,ay5,ay6,ay7;
    float bx0,bx1,bx2,bx3,bx4,bx5,bx6,bx7;
    float by0,by1,by2,by3,by4,by5,by6,by7;
    {
        const float4* pa = (const float4*)(A + (size_t)i * 16);
        const float4* pb = (const float4*)(Bq + (size_t)i * 16);
        float4 q;
        q = pa[0]; ax0=q.x; ay0=q.y; ax1=q.z; ay1=q.w;
        q = pa[1]; ax2=q.x; ay2=q.y; ax3=q.z; ay3=q.w;
        q = pa[2]; ax4=q.x; ay4=q.y; ax5=q.z; ay5=q.w;
        q = pa[3]; ax6=q.x; ay6=q.y; ax7=q.z; ay7=q.w;
        q = pb[0]; bx0=q.x; by0=q.y; bx1=q.z; by1=q.w;
        q = pb[1]; bx2=q.x; by2=q.y; bx3=q.z; by3=q.w;
        q = pb[2]; bx4=q.x; by4=q.y; bx5=q.z; by5=q.w;
        q = pb[3]; bx6=q.x; by6=q.y; bx7=q.z; by7=q.w;
    }

    // Shoelace terms; ca_i = cross(A_i,A_{i+1}), cb_j = cross(B_j,B_{j+1}).
#define MKCA(I,IN) float ca##I = ax##I*ay##IN - ay##I*ax##IN;
#define MKCB(I,IN) float cb##I = bx##I*by##IN - by##I*bx##IN;
    MKCA(0,1) MKCA(1,2) MKCA(2,3) MKCA(3,4)
    MKCA(4,5) MKCA(5,6) MKCA(6,7) MKCA(7,0)
    MKCB(0,1) MKCB(1,2) MKCB(2,3) MKCB(3,4)
    MKCB(4,5) MKCB(5,6) MKCB(6,7) MKCB(7,0)
    float area_a = 0.5f * (((ca0+ca1)+(ca2+ca3)) + ((ca4+ca5)+(ca6+ca7)));
    float area_b = 0.5f * (((cb0+cb1)+(cb2+cb3)) + ((cb4+cb5)+(cb6+cb7)));

    // ---- Intersection: Green's theorem over clipped edges ----
    // inside Q iff aa + t*bb >= 0 along P-edge; h = bb*1e38 absorbs the
    // unused min/max arm (bb==0 parallel case measure-zero, r10+).
    float inter2 = 0.f;

#define DTST(I) float t0a##I=0.f,t1a##I=1.f,t0b##I=0.f,t1b##I=1.f;
#define PU(I,IN,T0P,T1P) { \
        float bb = s##IN - s##I; \
        float tc = __fdividef(-s##I, bb); \
        float h = bb * 1e38f; \
        T0P##I = fmaxf(T0P##I, fminf(tc, h)); \
        T1P##I = fminf(T1P##I, fmaxf(tc, h)); }

    // ---- Pass 1: A-edges clipped by B's half-planes ----
    {
        DTST(0) DTST(1) DTST(2) DTST(3) DTST(4) DTST(5) DTST(6) DTST(7)
#define DM1(I) float M##I = ax##I*by0 - ay##I*bx0;
        DM1(0) DM1(1) DM1(2) DM1(3) DM1(4) DM1(5) DM1(6) DM1(7)
        // step for B-halfplane j: M_i holds cross(A_i,B_j); N = cross(A_i,B_{j+1});
        // s_i = (M_i - N_i) + cb_j = cross(E_Bj, A_i - B_j); roll M.
#define P1N(I,BXN,BYN,CBJ) \
        float N##I = ax##I*(BYN) - ay##I*(BXN); \
        float s##I = (M##I - N##I) + (CBJ); M##I = N##I;
#define P1STEP(BXN,BYN,CBJ,T0P,T1P) { \
        P1N(0,BXN,BYN,CBJ) P1N(1,BXN,BYN,CBJ) P1N(2,BXN,BYN,CBJ) \
        P1N(3,BXN,BYN,CBJ) P1N(4,BXN,BYN,CBJ) P1N(5,BXN,BYN,CBJ) \
        P1N(6,BXN,BYN,CBJ) P1N(7,BXN,BYN,CBJ) \
        PU(0,1,T0P,T1P) PU(1,2,T0P,T1P) PU(2,3,T0P,T1P) PU(3,4,T0P,T1P) \
        PU(4,5,T0P,T1P) PU(5,6,T0P,T1P) PU(6,7,T0P,T1P) PU(7,0,T0P,T1P) }
        P1STEP(bx1,by1,cb0,t0a,t1a)   // j=0 -> 'a' (matches r20 HPB order)
        P1STEP(bx2,by2,cb1,t0b,t1b)
        P1STEP(bx3,by3,cb2,t0a,t1a)
        P1STEP(bx4,by4,cb3,t0b,t1b)
        P1STEP(bx5,by5,cb4,t0a,t1a)
        P1STEP(bx6,by6,cb5,t0b,t1b)
        P1STEP(bx7,by7,cb6,t0a,t1a)
        P1STEP(bx0,by0,cb7,t0b,t1b)
        // Green's sum over clipped A-edges; cpd = cross(A_i,A_{i+1}) = ca_i.
#define PE1(I) { \
        float dt = fminf(t1a##I,t1b##I) - fmaxf(t0a##I,t0b##I); \
        inter2 += fmaxf(dt, 0.f) * ca##I; }
        PE1(0) PE1(1) PE1(2) PE1(3) PE1(4) PE1(5) PE1(6) PE1(7)
    }

    // ---- Pass 2: B-edges clipped by A's half-planes ----
    {
        DTST(0) DTST(1) DTST(2) DTST(3) DTST(4) DTST(5) DTST(6) DTST(7)
#define DM2(J) float M##J = ax0*by##J - ay0*bx##J;
        DM2(0) DM2(1) DM2(2) DM2(3) DM2(4) DM2(5) DM2(6) DM2(7)
        // step for A-halfplane i: M_j holds cross(A_i,B_j); N = cross(A_{i+1},B_j);
        // s_j = (N_j - M_j) + ca_i = cross(E_Ai, B_j - A_i); roll M.
#define P2N(J,AXN,AYN,CAI) \
        float N##J = (AXN)*by##J - (AYN)*bx##J; \
        float s##J = (N##J - M##J) + (CAI); M##J = N##J;
#define P2STEP(AXN,AYN,CAI,T0P,T1P) { \
        P2N(0,AXN,AYN,CAI) P2N(1,AXN,AYN,CAI) P2N(2,AXN,AYN,CAI) \
        P2N(3,AXN,AYN,CAI) P2N(4,AXN,AYN,CAI) P2N(5,AXN,AYN,CAI) \
        P2N(6,AXN,AYN,CAI) P2N(7,AXN,AYN,CAI) \
        PU(0,1,T0P,T1P) PU(1,2,T0P,T1P) PU(2,3,T0P,T1P) PU(3,4,T0P,T1P) \
        PU(4,5,T0P,T1P) PU(5,6,T0P,T1P) PU(6,7,T0P,T1P) PU(7,0,T0P,T1P) }
        P2STEP(ax1,ay1,ca0,t0a,t1a)   // i=0 -> 'a' (matches r20 HPA order)
        P2STEP(ax2,ay2,ca1,t0b,t1b)
        P2STEP(ax3,ay3,ca2,t0a,t1a)
        P2STEP(ax4,ay4,ca3,t0b,t1b)
        P2STEP(ax5,ay5,ca4,t0a,t1a)
        P2STEP(ax6,ay6,ca5,t0b,t1b)
        P2STEP(ax7,ay7,ca6,t0a,t1a)
        P2STEP(ax0,ay0,ca7,t0b,t1b)
#define PE2(J) { \
        float dt = fminf(t1a##J,t1b##J) - fmaxf(t0a##J,t0b##J); \
        inter2 += fmaxf(dt, 0.f) * cb##J; }
        PE2(0) PE2(1) PE2(2) PE2(3) PE2(4) PE2(5) PE2(6) PE2(7)
    }

    float inter = fmaxf(0.5f * inter2, 0.f);
    float uni = area_a + area_b - inter;
    float iou = __fdividef(inter, uni);

    // ---- Hull start: min by (y,x), 4-level tournament tree (r20) ----
#define MIN2(X1,Y1,X2,Y2) { \
        bool bs = ((Y2) < (Y1)) || (((Y2) == (Y1)) && ((X2) < (X1))); \
        X1 = bs ? (X2) : (X1); Y1 = bs ? (Y2) : (Y1); }
    float m0x=ax0, m0y=ay0; MIN2(m0x,m0y, ax1,ay1)
    float m1x=ax2, m1y=ay2; MIN2(m1x,m1y, ax3,ay3)
    float m2x=ax4, m2y=ay4; MIN2(m2x,m2y, ax5,ay5)
    float m3x=ax6, m3y=ay6; MIN2(m3x,m3y, ax7,ay7)
    float m4x=bx0, m4y=by0; MIN2(m4x,m4y, bx1,by1)
    float m5x=bx2, m5y=by2; MIN2(m5x,m5y, bx3,by3)
    float m6x=bx4, m6y=by4; MIN2(m6x,m6y, bx5,by5)
    float m7x=bx6, m7y=by6; MIN2(m7x,m7y, bx7,by7)
    MIN2(m0x,m0y, m1x,m1y) MIN2(m2x,m2y, m3x,m3y)
    MIN2(m4x,m4y, m5x,m5y) MIN2(m6x,m6y, m7x,m7y)
    MIN2(m0x,m0y, m2x,m2y) MIN2(m4x,m4y, m6x,m6y)
    MIN2(m0x,m0y, m4x,m4y)
    const float stx = m0x, sty = m0y;

    // ---- Jarvis march, 8-chain split tournament (r20, unchanged) ----
#define SCANC(CDX,CDY,NX,NY,PX,PY) { \
        float vx = (PX) - cxv, vy = (PY) - cyv; \
        float cr = CDX*vy - CDY*vx; \
        bool take = cr < 0.f; \
        NX = take ? (PX) : NX;  NY = take ? (PY) : NY; \
        CDX = take ? vx : CDX;  CDY = take ? vy : CDY; }
#define MERGE(CDX,CDY,NX,NY,CDX2,CDY2,NX2,NY2) { \
        float cr = CDX*(CDY2) - CDY*(CDX2); \
        bool take = cr < 0.f; \
        NX = take ? (NX2) : NX;  NY = take ? (NY2) : NY; \
        CDX = take ? (CDX2) : CDX; CDY = take ? (CDY2) : CDY; }

    float cxv = stx, cyv = sty, accH = 0.f;
    float pdx = 1.f, pdy = 0.f;          // reference's initial heading (1,0)
    bool done = false;
#pragma unroll 1
    for (int it = 0; it < 16; ++it) {
        float ndx = -pdx, ndy = -pdy;
        float cdx0 = ndx, cdy0 = ndy, nx0 = cxv, ny0 = cyv;
        float cdx1 = ndx, cdy1 = ndy, nx1 = cxv, ny1 = cyv;
        float cdx2 = ndx, cdy2 = ndy, nx2 = cxv, ny2 = cyv;
        float cdx3 = ndx, cdy3 = ndy, nx3 = cxv, ny3 = cyv;
        float cdx4 = ndx, cdy4 = ndy, nx4 = cxv, ny4 = cyv;
        float cdx5 = ndx, cdy5 = ndy, nx5 = cxv, ny5 = cyv;
        float cdx6 = ndx, cdy6 = ndy, nx6 = cxv, ny6 = cyv;
        float cdx7 = ndx, cdy7 = ndy, nx7 = cxv, ny7 = cyv;
        SCANC(cdx0,cdy0,nx0,ny0, ax0,ay0) SCANC(cdx0,cdy0,nx0,ny0, ax1,ay1)
        SCANC(cdx1,cdy1,nx1,ny1, ax2,ay2) SCANC(cdx1,cdy1,nx1,ny1, ax3,ay3)
        SCANC(cdx2,cdy2,nx2,ny2, ax4,ay4) SCANC(cdx2,cdy2,nx2,ny2, ax5,ay5)
        SCANC(cdx3,cdy3,nx3,ny3, ax6,ay6) SCANC(cdx3,cdy3,nx3,ny3, ax7,ay7)
        SCANC(cdx4,cdy4,nx4,ny4, bx0,by0) SCANC(cdx4,cdy4,nx4,ny4, bx1,by1)
        SCANC(cdx5,cdy5,nx5,ny5, bx2,by2) SCANC(cdx5,cdy5,nx5,ny5, bx3,by3)
        SCANC(cdx6,cdy6,nx6,ny6, bx4,by4) SCANC(cdx6,cdy6,nx6,ny6, bx5,by5)
        SCANC(cdx7,cdy7,nx7,ny7, bx6,by6) SCANC(cdx7,cdy7,nx7,ny7, bx7,by7)
        MERGE(cdx0,cdy0,nx0,ny0, cdx1,cdy1,nx1,ny1)
        MERGE(cdx2,cdy2,nx2,ny2, cdx3,cdy3,nx3,ny3)
        MERGE(cdx4,cdy4,nx4,ny4, cdx5,cdy5,nx5,ny5)
        MERGE(cdx6,cdy6,nx6,ny6, cdx7,cdy7,nx7,ny7)
        MERGE(cdx0,cdy0,nx0,ny0, cdx2,cdy2,nx2,ny2)
        MERGE(cdx4,cdy4,nx4,ny4, cdx6,cdy6,nx6,ny6)
        MERGE(cdx0,cdy0,nx0,ny0, cdx4,cdy4,nx4,ny4)
        accH += done ? 0.f : (cxv*ny0 - cyv*nx0);
        done = done || (nx0 == stx && ny0 == sty);
        pdx = cdx0; pdy = cdy0;
        cxv = nx0; cyv = ny0;
        if (__all(done)) break;
    }
    float ch = 0.5f * accH;

    float val = iou - __fdividef(ch - uni, ch);
    float v = live ? val : 0.f;

    // ---- epilogue: shuffle -> LDS(16B) -> ONE plain store. Zero waits. ----
    #pragma unroll
    for (int off = 32; off > 0; off >>= 1) v += __shfl_down(v, off);
    __shared__ float wsum[4];
    int lane = t & 63, wid = t >> 6;
    if (lane == 0) wsum[wid] = v;
    __syncthreads();
    if (t == 0) {
        partial[blockIdx.x] = (double)wsum[0] + (double)wsum[1]
                            + (double)wsum[2] + (double)wsum[3];
    }
}

__global__ __launch_bounds__(256) void ciou_finalize(
    const double* __restrict__ partial, float* __restrict__ out,
    int nparts, int nbatch)
{
    double v = 0.0;
    for (int j = threadIdx.x; j < nparts; j += 256) v += partial[j];
    #pragma unroll
    for (int off = 32; off > 0; off >>= 1) v += __shfl_down(v, off);
    __shared__ double s[4];
    int lane = threadIdx.x & 63, wid = threadIdx.x >> 6;
    if (lane == 0) s[wid] = v;
    __syncthreads();
    if (threadIdx.x == 0)
        out[0] = (float)((s[0] + s[1] + s[2] + s[3]) / (double)nbatch);
}

extern "C" void kernel_launch(void* const* d_in, const int* in_sizes, int n_in,
                              void* d_out, int out_size, void* d_ws, size_t ws_size,
                              hipStream_t stream) {
    const float* a = (const float*)d_in[0];
    const float* b = (const float*)d_in[1];
    float* out = (float*)d_out;
    int nbatch = in_sizes[0] / 16;
    int nblocks = (nbatch + TPB - 1) / TPB;   // 262144 -> 1024, exact
    int tail = (nblocks * TPB != nbatch) ? 1 : 0;
    double* partial = (double*)d_ws;   // fully overwritten each call; no memset
    ciou_main<<<nblocks, TPB, 0, stream>>>(a, b, partial, nbatch, tail);
    ciou_finalize<<<1, 256, 0, stream>>>(partial, out, nblocks, nbatch);
}

// Round 8
// 100.148 us; speedup vs baseline: 1.1157x; 1.1157x over previous
//
#include <hip/hip_runtime.h>

#define TPB 256

// r22 (resubmit — r7 bench was an infra failure, kernel never ran).
// Salvage r21's algebra WITHOUT its register blow-up.
// r21 lessons: (a) reassociated clip still gives absmax 0.0 (262k zero-mean
// errors average below the output ulp) -> non-bit-exact algebra allowed;
// (b) the rolling-M matrix form kept ~36 extra values live -> 38 MB of
// scratch spill (WRITE_SIZE), main 42->48.6us. Fix: keep r20's EDGE/HP
// structure (temps die within each HP) and only hoist per-edge constants:
//   edge vectors ea_i, eb_j (32 regs) + shoelace crosses ca_i, cb_j:
//   aa = ebx*Py - eby*Px + cb_j   (2 FMA; was 4 subs + mul + fma)
//   bb = ebx*Dy - eby*Dx          (ex/ey subtractions hoisted)
//   cpd = ca_i (free), shoelace = sums of ca/cb (free).
// Live set ~95-115 VGPR < 128 -> 4 waves/SIMD kept. launch_bounds (256,2)
// as in the proven r18/r20 config. Hull tree, 8-chain Jarvis, epilogue,
// finalize: byte-identical to r20.
__global__ __launch_bounds__(TPB, 2) void ciou_main(
    const float* __restrict__ A,
    const float* __restrict__ Bq,
    double* __restrict__ partial,
    int nbatch, int tail)
{
    const int t = threadIdx.x;
    const int i0 = blockIdx.x * TPB + t;
    const bool live = !tail || (i0 < nbatch);
    const int i = live ? i0 : (nbatch - 1);

    float ax0,ax1,ax2,ax3,ax4,ax5,ax6,ax7;
    float ay0,ay1,ay2,ay3,ay4,ay5,ay6,ay7;
    float bx0,bx1,bx2,bx3,bx4,bx5,bx6,bx7;
    float by0,by1,by2,by3,by4,by5,by6,by7;
    {
        const float4* pa = (const float4*)(A + (size_t)i * 16);
        const float4* pb = (const float4*)(Bq + (size_t)i * 16);
        float4 q;
        q = pa[0]; ax0=q.x; ay0=q.y; ax1=q.z; ay1=q.w;
        q = pa[1]; ax2=q.x; ay2=q.y; ax3=q.z; ay3=q.w;
        q = pa[2]; ax4=q.x; ay4=q.y; ax5=q.z; ay5=q.w;
        q = pa[3]; ax6=q.x; ay6=q.y; ax7=q.z; ay7=q.w;
        q = pb[0]; bx0=q.x; by0=q.y; bx1=q.z; by1=q.w;
        q = pb[1]; bx2=q.x; by2=q.y; bx3=q.z; by3=q.w;
        q = pb[2]; bx4=q.x; by4=q.y; bx5=q.z; by5=q.w;
        q = pb[3]; bx6=q.x; by6=q.y; bx7=q.z; by7=q.w;
    }

    // Edge vectors and shoelace crosses (hoisted once, reused everywhere).
#define MKEA(I,IN) float eax##I = ax##IN - ax##I, eay##I = ay##IN - ay##I;
#define MKEB(I,IN) float ebx##I = bx##IN - bx##I, eby##I = by##IN - by##I;
    MKEA(0,1) MKEA(1,2) MKEA(2,3) MKEA(3,4)
    MKEA(4,5) MKEA(5,6) MKEA(6,7) MKEA(7,0)
    MKEB(0,1) MKEB(1,2) MKEB(2,3) MKEB(3,4)
    MKEB(4,5) MKEB(5,6) MKEB(6,7) MKEB(7,0)
#define MKCA(I,IN) float ca##I = ax##I*ay##IN - ay##I*ax##IN;
#define MKCB(I,IN) float cb##I = bx##I*by##IN - by##I*bx##IN;
    MKCA(0,1) MKCA(1,2) MKCA(2,3) MKCA(3,4)
    MKCA(4,5) MKCA(5,6) MKCA(6,7) MKCA(7,0)
    MKCB(0,1) MKCB(1,2) MKCB(2,3) MKCB(3,4)
    MKCB(4,5) MKCB(5,6) MKCB(6,7) MKCB(7,0)
    float area_a = 0.5f * (((ca0+ca1)+(ca2+ca3)) + ((ca4+ca5)+(ca6+ca7)));
    float area_b = 0.5f * (((cb0+cb1)+(cb2+cb3)) + ((cb4+cb5)+(cb6+cb7)));

    // ---- Intersection: Green's theorem over clipped edges ----
    float inter2 = 0.f;

    // inside halfplane j iff cross(E_j, P - Q0_j) = EX*Py - EY*Px + CC >= 0
    // (CC = cross(Q0,Q1) since cross(E,Q0) = -CC). Along edge: aa + t*bb.
    // Branchless h = bb*1e38 absorbs the unused min/max arm (r10+, bb==0
    // parallel case measure-zero).
#define HP(T0,T1,EX,EY,CC) { \
        float aa = EX*Py - EY*Px + (CC); \
        float bb = EX*Dy - EY*Dx; \
        float tc = __fdividef(-aa, bb); \
        float h = bb * 1e38f; \
        T0 = fmaxf(T0, fminf(tc, h)); \
        T1 = fminf(T1, fmaxf(tc, h)); }

#define HPB HP(t0a,t1a, ebx0,eby0,cb0) HP(t0b,t1b, ebx1,eby1,cb1) \
            HP(t0a,t1a, ebx2,eby2,cb2) HP(t0b,t1b, ebx3,eby3,cb3) \
            HP(t0a,t1a, ebx4,eby4,cb4) HP(t0b,t1b, ebx5,eby5,cb5) \
            HP(t0a,t1a, ebx6,eby6,cb6) HP(t0b,t1b, ebx7,eby7,cb7)
#define HPA HP(t0a,t1a, eax0,eay0,ca0) HP(t0b,t1b, eax1,eay1,ca1) \
            HP(t0a,t1a, eax2,eay2,ca2) HP(t0b,t1b, eax3,eay3,ca3) \
            HP(t0a,t1a, eax4,eay4,ca4) HP(t0b,t1b, eax5,eay5,ca5) \
            HP(t0a,t1a, eax6,eay6,ca6) HP(t0b,t1b, eax7,eay7,ca7)

    // cross(P(t0),P(t1)) = (t1-t0)*cross(P,D); cross(P,D) = cross(P,Pn) = CPD
    // (precomputed shoelace term). dt<=0 -> fmax gives exact 0.
#define EDGE(PX,PY,DX,DY,CPD,HPS) { \
        const float Px = (PX), Py = (PY); \
        const float Dx = (DX), Dy = (DY); \
        float t0a = 0.f, t1a = 1.f, t0b = 0.f, t1b = 1.f; \
        HPS \
        float dt = fminf(t1a, t1b) - fmaxf(t0a, t0b); \
        inter2 += fmaxf(dt, 0.f) * (CPD); }

    EDGE(ax0,ay0, eax0,eay0, ca0, HPB) EDGE(ax1,ay1, eax1,eay1, ca1, HPB)
    EDGE(ax2,ay2, eax2,eay2, ca2, HPB) EDGE(ax3,ay3, eax3,eay3, ca3, HPB)
    EDGE(ax4,ay4, eax4,eay4, ca4, HPB) EDGE(ax5,ay5, eax5,eay5, ca5, HPB)
    EDGE(ax6,ay6, eax6,eay6, ca6, HPB) EDGE(ax7,ay7, eax7,eay7, ca7, HPB)
    EDGE(bx0,by0, ebx0,eby0, cb0, HPA) EDGE(bx1,by1, ebx1,eby1, cb1, HPA)
    EDGE(bx2,by2, ebx2,eby2, cb2, HPA) EDGE(bx3,by3, ebx3,eby3, cb3, HPA)
    EDGE(bx4,by4, ebx4,eby4, cb4, HPA) EDGE(bx5,by5, ebx5,eby5, cb5, HPA)
    EDGE(bx6,by6, ebx6,eby6, cb6, HPA) EDGE(bx7,by7, ebx7,eby7, cb7, HPA)

    float inter = fmaxf(0.5f * inter2, 0.f);
    float uni = area_a + area_b - inter;
    float iou = __fdividef(inter, uni);

    // ---- Hull start: min by (y,x), 4-level tournament tree (r20) ----
#define MIN2(X1,Y1,X2,Y2) { \
        bool bs = ((Y2) < (Y1)) || (((Y2) == (Y1)) && ((X2) < (X1))); \
        X1 = bs ? (X2) : (X1); Y1 = bs ? (Y2) : (Y1); }
    float m0x=ax0, m0y=ay0; MIN2(m0x,m0y, ax1,ay1)
    float m1x=ax2, m1y=ay2; MIN2(m1x,m1y, ax3,ay3)
    float m2x=ax4, m2y=ay4; MIN2(m2x,m2y, ax5,ay5)
    float m3x=ax6, m3y=ay6; MIN2(m3x,m3y, ax7,ay7)
    float m4x=bx0, m4y=by0; MIN2(m4x,m4y, bx1,by1)
    float m5x=bx2, m5y=by2; MIN2(m5x,m5y, bx3,by3)
    float m6x=bx4, m6y=by4; MIN2(m6x,m6y, bx5,by5)
    float m7x=bx6, m7y=by6; MIN2(m7x,m7y, bx7,by7)
    MIN2(m0x,m0y, m1x,m1y) MIN2(m2x,m2y, m3x,m3y)
    MIN2(m4x,m4y, m5x,m5y) MIN2(m6x,m6y, m7x,m7y)
    MIN2(m0x,m0y, m2x,m2y) MIN2(m4x,m4y, m6x,m6y)
    MIN2(m0x,m0y, m4x,m4y)
    const float stx = m0x, sty = m0y;

    // ---- Jarvis march, 8-chain split tournament (r20, unchanged) ----
#define SCANC(CDX,CDY,NX,NY,PX,PY) { \
        float vx = (PX) - cxv, vy = (PY) - cyv; \
        float cr = CDX*vy - CDY*vx; \
        bool take = cr < 0.f; \
        NX = take ? (PX) : NX;  NY = take ? (PY) : NY; \
        CDX = take ? vx : CDX;  CDY = take ? vy : CDY; }
#define MERGE(CDX,CDY,NX,NY,CDX2,CDY2,NX2,NY2) { \
        float cr = CDX*(CDY2) - CDY*(CDX2); \
        bool take = cr < 0.f; \
        NX = take ? (NX2) : NX;  NY = take ? (NY2) : NY; \
        CDX = take ? (CDX2) : CDX; CDY = take ? (CDY2) : CDY; }

    float cxv = stx, cyv = sty, accH = 0.f;
    float pdx = 1.f, pdy = 0.f;          // reference's initial heading (1,0)
    bool done = false;
#pragma unroll 1
    for (int it = 0; it < 16; ++it) {
        float ndx = -pdx, ndy = -pdy;
        float cdx0 = ndx, cdy0 = ndy, nx0 = cxv, ny0 = cyv;
        float cdx1 = ndx, cdy1 = ndy, nx1 = cxv, ny1 = cyv;
        float cdx2 = ndx, cdy2 = ndy, nx2 = cxv, ny2 = cyv;
        float cdx3 = ndx, cdy3 = ndy, nx3 = cxv, ny3 = cyv;
        float cdx4 = ndx, cdy4 = ndy, nx4 = cxv, ny4 = cyv;
        float cdx5 = ndx, cdy5 = ndy, nx5 = cxv, ny5 = cyv;
        float cdx6 = ndx, cdy6 = ndy, nx6 = cxv, ny6 = cyv;
        float cdx7 = ndx, cdy7 = ndy, nx7 = cxv, ny7 = cyv;
        SCANC(cdx0,cdy0,nx0,ny0, ax0,ay0) SCANC(cdx0,cdy0,nx0,ny0, ax1,ay1)
        SCANC(cdx1,cdy1,nx1,ny1, ax2,ay2) SCANC(cdx1,cdy1,nx1,ny1, ax3,ay3)
        SCANC(cdx2,cdy2,nx2,ny2, ax4,ay4) SCANC(cdx2,cdy2,nx2,ny2, ax5,ay5)
        SCANC(cdx3,cdy3,nx3,ny3, ax6,ay6) SCANC(cdx3,cdy3,nx3,ny3, ax7,ay7)
        SCANC(cdx4,cdy4,nx4,ny4, bx0,by0) SCANC(cdx4,cdy4,nx4,ny4, bx1,by1)
        SCANC(cdx5,cdy5,nx5,ny5, bx2,by2) SCANC(cdx5,cdy5,nx5,ny5, bx3,by3)
        SCANC(cdx6,cdy6,nx6,ny6, bx4,by4) SCANC(cdx6,cdy6,nx6,ny6, bx5,by5)
        SCANC(cdx7,cdy7,nx7,ny7, bx6,by6) SCANC(cdx7,cdy7,nx7,ny7, bx7,by7)
        MERGE(cdx0,cdy0,nx0,ny0, cdx1,cdy1,nx1,ny1)
        MERGE(cdx2,cdy2,nx2,ny2, cdx3,cdy3,nx3,ny3)
        MERGE(cdx4,cdy4,nx4,ny4, cdx5,cdy5,nx5,ny5)
        MERGE(cdx6,cdy6,nx6,ny6, cdx7,cdy7,nx7,ny7)
        MERGE(cdx0,cdy0,nx0,ny0, cdx2,cdy2,nx2,ny2)
        MERGE(cdx4,cdy4,nx4,ny4, cdx6,cdy6,nx6,ny6)
        MERGE(cdx0,cdy0,nx0,ny0, cdx4,cdy4,nx4,ny4)
        accH += done ? 0.f : (cxv*ny0 - cyv*nx0);
        done = done || (nx0 == stx && ny0 == sty);
        pdx = cdx0; pdy = cdy0;
        cxv = nx0; cyv = ny0;
        if (__all(done)) break;
    }
    float ch = 0.5f * accH;

    float val = iou - __fdividef(ch - uni, ch);
    float v = live ? val : 0.f;

    // ---- epilogue: shuffle -> LDS(16B) -> ONE plain store. Zero waits. ----
    #pragma unroll
    for (int off = 32; off > 0; off >>= 1) v += __shfl_down(v, off);
    __shared__ float wsum[4];
    int lane = t & 63, wid = t >> 6;
    if (lane == 0) wsum[wid] = v;
    __syncthreads();
    if (t == 0) {
        partial[blockIdx.x] = (double)wsum[0] + (double)wsum[1]
                            + (double)wsum[2] + (double)wsum[3];
    }
}

__global__ __launch_bounds__(256) void ciou_finalize(
    const double* __restrict__ partial, float* __restrict__ out,
    int nparts, int nbatch)
{
    double v = 0.0;
    for (int j = threadIdx.x; j < nparts; j += 256) v += partial[j];
    #pragma unroll
    for (int off = 32; off > 0; off >>= 1) v += __shfl_down(v, off);
    __shared__ double s[4];
    int lane = threadIdx.x & 63, wid = threadIdx.x >> 6;
    if (lane == 0) s[wid] = v;
    __syncthreads();
    if (threadIdx.x == 0)
        out[0] = (float)((s[0] + s[1] + s[2] + s[3]) / (double)nbatch);
}

extern "C" void kernel_launch(void* const* d_in, const int* in_sizes, int n_in,
                              void* d_out, int out_size, void* d_ws, size_t ws_size,
                              hipStream_t stream) {
    const float* a = (const float*)d_in[0];
    const float* b = (const float*)d_in[1];
    float* out = (float*)d_out;
    int nbatch = in_sizes[0] / 16;
    int nblocks = (nbatch + TPB - 1) / TPB;   // 262144 -> 1024, exact
    int tail = (nblocks * TPB != nbatch) ? 1 : 0;
    double* partial = (double*)d_ws;   // fully overwritten each call; no memset
    ciou_main<<<nblocks, TPB, 0, stream>>>(a, b, partial, nbatch, tail);
    ciou_finalize<<<1, 256, 0, stream>>>(partial, out, nblocks, nbatch);
}